// Round 1
// baseline (293.877 us; speedup 1.0000x reference)
//
#include <hip/hip_runtime.h>
#include <hip/hip_bf16.h>

// Problem dims (fixed by setup_inputs)
#define Mdim 8192
#define Ndim 2048
#define Kdim 2048

#define BM 128
#define BN 128
#define BK 32

constexpr float kMin = -128.0f;
constexpr float kMax = 127.99609375f;
constexpr float kScale = 256.0f;
constexpr float kInvScale = 1.0f / 256.0f;
constexpr float kEps = 1e-5f;

typedef __attribute__((ext_vector_type(8))) short short8;
typedef __attribute__((ext_vector_type(4))) float f32x4;

__device__ __forceinline__ float fpq(float x) {
    x = fminf(fmaxf(x, kMin), kMax);
    return rintf(x * kScale) * kInvScale;   // rintf = round-half-to-even, matches jnp.round
}

__device__ __forceinline__ unsigned short f2bf(float f) {
    union { __hip_bfloat16 h; unsigned short u; } cv;
    cv.h = __float2bfloat16(f);             // round-to-nearest-even
    return cv.u;
}

__device__ __forceinline__ void gload_lds16(const void* g, void* l) {
    __builtin_amdgcn_global_load_lds(
        (const __attribute__((address_space(1))) unsigned int*)g,
        (__attribute__((address_space(3))) unsigned int*)l,
        16, 0, 0);
}

// ---------------------------------------------------------------------------
// Kernel 1: quantize weights to fixed-point grid, store as bf16 (exact here:
// |w|*256 < 32 so m*2^-8 fits bf16's 8-bit significand exactly).
__global__ void fpbn_quant_w(const float* __restrict__ w,
                             unsigned short* __restrict__ wb, int n4) {
    int i = blockIdx.x * blockDim.x + threadIdx.x;
    int stride = gridDim.x * blockDim.x;
    for (; i < n4; i += stride) {
        float4 v = ((const float4*)w)[i];
        ushort4 o;
        o.x = f2bf(fpq(v.x));
        o.y = f2bf(fpq(v.y));
        o.z = f2bf(fpq(v.z));
        o.w = f2bf(fpq(v.w));
        ((ushort4*)wb)[i] = o;
    }
}

// ---------------------------------------------------------------------------
// Kernel 2: bf16 MFMA GEMM y = fpq(fpq(x @ qw^T) + qb), y -> d_out (f32),
// plus per-column sum / sumsq partials via shuffle-reduce + atomics.
// 128x128 tile, BK=32, 4 waves (2x2), each wave 4x4 frags of 16x16x32.
__global__ __launch_bounds__(256) void fpbn_gemm(
    const float* __restrict__ x, const unsigned short* __restrict__ wb,
    const float* __restrict__ bias, float* __restrict__ y,
    float* __restrict__ colsum, float* __restrict__ colsumsq) {

    __shared__ unsigned short As[BM][BK];   // 8 KB
    __shared__ unsigned short Bs[BN][BK];   // 8 KB

    const int t    = threadIdx.x;
    const int lane = t & 63;
    const int w    = t >> 6;
    const int wm   = w >> 1;            // 0..1
    const int wn   = w & 1;             // 0..1
    const int bm   = blockIdx.x & (Mdim / BM - 1);   // 64 row tiles
    const int bn   = blockIdx.x >> 6;                // 16 col tiles
    const int row0 = bm * BM;
    const int col0 = bn * BN;

    // A staging (reg-staged f32 -> bf16): thread covers 16 consecutive floats
    const int ar = t >> 1;              // row 0..127
    const int ah = (t & 1) * 16;        // elem offset within row
    const float4* gA = (const float4*)(x + (size_t)(row0 + ar) * Kdim + ah);

    // B staging via global_load_lds: thread t owns LDS bytes [t*16, t*16+16)
    const unsigned short* gB0 = wb + (size_t)(col0 + (t >> 2)) * Kdim + (t & 3) * 8;
    const unsigned short* gB1 = wb + (size_t)(col0 + 64 + (t >> 2)) * Kdim + (t & 3) * 8;
    unsigned short* ldsB0 = &Bs[0][0] + t * 8;          // t*16 bytes
    unsigned short* ldsB1 = &Bs[0][0] + 2048 + t * 8;   // +4096 bytes

    f32x4 acc[4][4] = {};

    for (int k0 = 0; k0 < Kdim; k0 += BK) {
        __syncthreads();   // previous tile fully consumed; LDS reusable

        // async B tile -> LDS (2 x 4KB)
        gload_lds16(gB0 + k0, ldsB0);
        gload_lds16(gB1 + k0, ldsB1);

        // A: load 16 f32, convert, ds_write 32B
        const int q = k0 >> 2;
        float4 f0 = gA[q + 0], f1 = gA[q + 1], f2 = gA[q + 2], f3 = gA[q + 3];
        uint4 d0, d1;
        d0.x = (unsigned)f2bf(f0.x) | ((unsigned)f2bf(f0.y) << 16);
        d0.y = (unsigned)f2bf(f0.z) | ((unsigned)f2bf(f0.w) << 16);
        d0.z = (unsigned)f2bf(f1.x) | ((unsigned)f2bf(f1.y) << 16);
        d0.w = (unsigned)f2bf(f1.z) | ((unsigned)f2bf(f1.w) << 16);
        d1.x = (unsigned)f2bf(f2.x) | ((unsigned)f2bf(f2.y) << 16);
        d1.y = (unsigned)f2bf(f2.z) | ((unsigned)f2bf(f2.w) << 16);
        d1.z = (unsigned)f2bf(f3.x) | ((unsigned)f2bf(f3.y) << 16);
        d1.w = (unsigned)f2bf(f3.z) | ((unsigned)f2bf(f3.w) << 16);
        uint4* dst = (uint4*)&As[ar][ah];
        dst[0] = d0;
        dst[1] = d1;

        __syncthreads();   // drains vmcnt (global_load_lds) + lgkm (ds_write)

        short8 af[4], bf[4];
#pragma unroll
        for (int m = 0; m < 4; ++m)
            af[m] = *(const short8*)&As[wm * 64 + m * 16 + (lane & 15)][(lane >> 4) * 8];
#pragma unroll
        for (int n = 0; n < 4; ++n)
            bf[n] = *(const short8*)&Bs[wn * 64 + n * 16 + (lane & 15)][(lane >> 4) * 8];
#pragma unroll
        for (int m = 0; m < 4; ++m)
#pragma unroll
            for (int n = 0; n < 4; ++n)
                acc[m][n] = __builtin_amdgcn_mfma_f32_16x16x32_bf16(
                    af[m], bf[n], acc[m][n], 0, 0, 0);
    }

    // Epilogue: quantize, add quantized bias, write y, column stats.
    // C/D layout (m89): col = lane&15, row = (lane>>4)*4 + j
#pragma unroll
    for (int n = 0; n < 4; ++n) {
        const int col = col0 + wn * 64 + n * 16 + (lane & 15);
        const float qb = fpq(bias[col]);
        float s = 0.0f, s2 = 0.0f;
#pragma unroll
        for (int m = 0; m < 4; ++m) {
            const int rowb = row0 + wm * 64 + m * 16 + ((lane >> 4) * 4);
#pragma unroll
            for (int j = 0; j < 4; ++j) {
                float v = fpq(acc[m][n][j]);
                v = fpq(v + qb);   // grid-aligned: clamp only in practice
                y[(size_t)(rowb + j) * Ndim + col] = v;
                s += v;
                s2 += v * v;
            }
        }
        // lanes {l, l^16, l^32, l^48} share this column -> reduce, one atomic
        s  += __shfl_xor(s, 16, 64);  s  += __shfl_xor(s, 32, 64);
        s2 += __shfl_xor(s2, 16, 64); s2 += __shfl_xor(s2, 32, 64);
        if (lane < 16) {
            atomicAdd(&colsum[col], s);
            atomicAdd(&colsumsq[col], s2);
        }
    }
}

// ---------------------------------------------------------------------------
// Kernel 3: per-column BN coefficients a,b
__global__ void fpbn_finalize(const float* __restrict__ colsum,
                              const float* __restrict__ colsumsq,
                              const float* __restrict__ gamma,
                              const float* __restrict__ beta,
                              float* __restrict__ a, float* __restrict__ b) {
    int i = blockIdx.x * blockDim.x + threadIdx.x;
    if (i < Ndim) {
        float mean = colsum[i] * (1.0f / Mdim);
        float var  = colsumsq[i] * (1.0f / Mdim) - mean * mean;
        float inv  = 1.0f / sqrtf(var + kEps);
        float ai   = gamma[i] * inv;
        a[i] = ai;
        b[i] = beta[i] - mean * ai;
    }
}

// ---------------------------------------------------------------------------
// Kernel 4: in-place BN apply + final quantize (read-modify-write same addr)
__global__ void fpbn_apply(float* __restrict__ y,
                           const float* __restrict__ a,
                           const float* __restrict__ b, int n4) {
    int i = blockIdx.x * blockDim.x + threadIdx.x;
    int stride = gridDim.x * blockDim.x;
    for (; i < n4; i += stride) {
        float4 v = ((float4*)y)[i];
        int cb = (i * 4) & (Ndim - 1);
        float4 av = *(const float4*)&a[cb];
        float4 bv = *(const float4*)&b[cb];
        v.x = fpq(fmaf(av.x, v.x, bv.x));
        v.y = fpq(fmaf(av.y, v.y, bv.y));
        v.z = fpq(fmaf(av.z, v.z, bv.z));
        v.w = fpq(fmaf(av.w, v.w, bv.w));
        ((float4*)y)[i] = v;
    }
}

// ---------------------------------------------------------------------------
extern "C" void kernel_launch(void* const* d_in, const int* in_sizes, int n_in,
                              void* d_out, int out_size, void* d_ws, size_t ws_size,
                              hipStream_t stream) {
    const float* x      = (const float*)d_in[0];
    const float* weight = (const float*)d_in[1];
    const float* bias   = (const float*)d_in[2];
    const float* gamma  = (const float*)d_in[3];
    const float* beta   = (const float*)d_in[4];
    float* out = (float*)d_out;

    // ws layout (~8.05 MB): wb bf16 [2048*2048] | colsum[2048] | colsumsq[2048] | a[2048] | b[2048]
    char* ws = (char*)d_ws;
    unsigned short* wb = (unsigned short*)ws;
    float* colsum   = (float*)(ws + (size_t)Ndim * Kdim * 2);
    float* colsumsq = colsum + Ndim;
    float* aArr     = colsum + 2 * Ndim;
    float* bArr     = colsum + 3 * Ndim;

    hipMemsetAsync(colsum, 0, 2 * Ndim * sizeof(float), stream);

    fpbn_quant_w<<<1024, 256, 0, stream>>>(weight, wb, Ndim * Kdim / 4);

    fpbn_gemm<<<(Mdim / BM) * (Ndim / BN), 256, 0, stream>>>(
        x, wb, bias, out, colsum, colsumsq);

    fpbn_finalize<<<(Ndim + 255) / 256, 256, 0, stream>>>(
        colsum, colsumsq, gamma, beta, aArr, bArr);

    fpbn_apply<<<2048, 256, 0, stream>>>(out, aArr, bArr,
                                         Mdim * Ndim / 4);
}

// Round 2
// 250.238 us; speedup vs baseline: 1.1744x; 1.1744x over previous
//
#include <hip/hip_runtime.h>
#include <hip/hip_bf16.h>

// Problem dims (fixed by setup_inputs)
#define Mdim 8192
#define Ndim 2048
#define Kdim 2048

#define BM 128
#define BN 128
#define BK 32

constexpr float kMin = -128.0f;
constexpr float kMax = 127.99609375f;
constexpr float kScale = 256.0f;
constexpr float kInvScale = 1.0f / 256.0f;
constexpr float kEps = 1e-5f;

typedef __attribute__((ext_vector_type(8))) short short8;
typedef __attribute__((ext_vector_type(4))) float f32x4;

__device__ __forceinline__ float fpq(float x) {
    x = fminf(fmaxf(x, kMin), kMax);
    return rintf(x * kScale) * kInvScale;   // rintf = round-half-to-even, matches jnp.round
}

__device__ __forceinline__ unsigned short f2bf(float f) {
    union { __hip_bfloat16 h; unsigned short u; } cv;
    cv.h = __float2bfloat16(f);             // round-to-nearest-even
    return cv.u;
}

__device__ __forceinline__ void gload_lds16(const void* g, void* l) {
    __builtin_amdgcn_global_load_lds(
        (const __attribute__((address_space(1))) unsigned int*)g,
        (__attribute__((address_space(3))) unsigned int*)l,
        16, 0, 0);
}

// ---------------------------------------------------------------------------
// Kernel 1a: quantize weights to fixed-point grid, store as bf16 (exact here:
// |w|*256 < 32 so m*2^-8 fits bf16's 8-bit significand exactly).
__global__ void fpbn_quant_w(const float* __restrict__ w,
                             unsigned short* __restrict__ wb, int n4) {
    int i = blockIdx.x * blockDim.x + threadIdx.x;
    int stride = gridDim.x * blockDim.x;
    for (; i < n4; i += stride) {
        float4 v = ((const float4*)w)[i];
        ushort4 o;
        o.x = f2bf(fpq(v.x));
        o.y = f2bf(fpq(v.y));
        o.z = f2bf(fpq(v.z));
        o.w = f2bf(fpq(v.w));
        ((ushort4*)wb)[i] = o;
    }
}

// Kernel 1b: convert x f32 -> bf16 (RNE), 32B in / 16B out per iteration.
__global__ void fpbn_quant_x(const float* __restrict__ x,
                             unsigned short* __restrict__ xb, int n8) {
    int i = blockIdx.x * blockDim.x + threadIdx.x;
    int stride = gridDim.x * blockDim.x;
    for (; i < n8; i += stride) {
        float4 a = ((const float4*)x)[2 * i];
        float4 b = ((const float4*)x)[2 * i + 1];
        uint4 o;
        o.x = (unsigned)f2bf(a.x) | ((unsigned)f2bf(a.y) << 16);
        o.y = (unsigned)f2bf(a.z) | ((unsigned)f2bf(a.w) << 16);
        o.z = (unsigned)f2bf(b.x) | ((unsigned)f2bf(b.y) << 16);
        o.w = (unsigned)f2bf(b.z) | ((unsigned)f2bf(b.w) << 16);
        ((uint4*)xb)[i] = o;
    }
}

// ---------------------------------------------------------------------------
// Kernel 2 (fast path): pure m97-structure bf16 MFMA GEMM.
// Both A and B tiles staged via global_load_lds width-16 (4 insts/thread/K-tile).
// y = fpq(fpq(x @ qw^T) + qb) -> d_out (f32), plus column sum/sumsq atomics.
__global__ __launch_bounds__(256) void fpbn_gemm_bb(
    const unsigned short* __restrict__ xb, const unsigned short* __restrict__ wb,
    const float* __restrict__ bias, float* __restrict__ y,
    float* __restrict__ colsum, float* __restrict__ colsumsq) {

    __shared__ unsigned short As[BM][BK];   // 8 KB
    __shared__ unsigned short Bs[BN][BK];   // 8 KB

    const int t    = threadIdx.x;
    const int lane = t & 63;
    const int w    = t >> 6;
    const int wm   = w >> 1;            // 0..1
    const int wn   = w & 1;             // 0..1
    const int bm   = blockIdx.x & (Mdim / BM - 1);   // 64 row tiles
    const int bn   = blockIdx.x >> 6;                // 16 col tiles
    const int row0 = bm * BM;
    const int col0 = bn * BN;

    // staging: thread t owns LDS bytes [t*16, t*16+16) of each 4KB half-tile
    const unsigned short* gA0 = xb + (size_t)(row0 + (t >> 2)) * Kdim + (t & 3) * 8;
    const unsigned short* gA1 = xb + (size_t)(row0 + 64 + (t >> 2)) * Kdim + (t & 3) * 8;
    const unsigned short* gB0 = wb + (size_t)(col0 + (t >> 2)) * Kdim + (t & 3) * 8;
    const unsigned short* gB1 = wb + (size_t)(col0 + 64 + (t >> 2)) * Kdim + (t & 3) * 8;
    unsigned short* ldsA0 = &As[0][0] + t * 8;
    unsigned short* ldsA1 = &As[0][0] + 2048 + t * 8;
    unsigned short* ldsB0 = &Bs[0][0] + t * 8;
    unsigned short* ldsB1 = &Bs[0][0] + 2048 + t * 8;

    f32x4 acc[4][4] = {};

    for (int k0 = 0; k0 < Kdim; k0 += BK) {
        __syncthreads();   // previous tile fully consumed

        gload_lds16(gA0 + k0, ldsA0);
        gload_lds16(gA1 + k0, ldsA1);
        gload_lds16(gB0 + k0, ldsB0);
        gload_lds16(gB1 + k0, ldsB1);

        __syncthreads();   // drains vmcnt -> tiles resident

        short8 af[4], bf[4];
#pragma unroll
        for (int m = 0; m < 4; ++m)
            af[m] = *(const short8*)&As[wm * 64 + m * 16 + (lane & 15)][(lane >> 4) * 8];
#pragma unroll
        for (int n = 0; n < 4; ++n)
            bf[n] = *(const short8*)&Bs[wn * 64 + n * 16 + (lane & 15)][(lane >> 4) * 8];
#pragma unroll
        for (int m = 0; m < 4; ++m)
#pragma unroll
            for (int n = 0; n < 4; ++n)
                acc[m][n] = __builtin_amdgcn_mfma_f32_16x16x32_bf16(
                    af[m], bf[n], acc[m][n], 0, 0, 0);
    }

    // Epilogue: quantize, add quantized bias, write y, column stats.
    // C/D layout (m89): col = lane&15, row = (lane>>4)*4 + j
#pragma unroll
    for (int n = 0; n < 4; ++n) {
        const int col = col0 + wn * 64 + n * 16 + (lane & 15);
        const float qb = fpq(bias[col]);
        float s = 0.0f, s2 = 0.0f;
#pragma unroll
        for (int m = 0; m < 4; ++m) {
            const int rowb = row0 + wm * 64 + m * 16 + ((lane >> 4) * 4);
#pragma unroll
            for (int j = 0; j < 4; ++j) {
                float v = fpq(acc[m][n][j]);
                v = fpq(v + qb);
                y[(size_t)(rowb + j) * Ndim + col] = v;
                s += v;
                s2 += v * v;
            }
        }
        s  += __shfl_xor(s, 16, 64);  s  += __shfl_xor(s, 32, 64);
        s2 += __shfl_xor(s2, 16, 64); s2 += __shfl_xor(s2, 32, 64);
        if (lane < 16) {
            atomicAdd(&colsum[col], s);
            atomicAdd(&colsumsq[col], s2);
        }
    }
}

// ---------------------------------------------------------------------------
// Kernel 2 (fallback, ws too small): reg-staged A from f32 (round-0 kernel).
__global__ __launch_bounds__(256) void fpbn_gemm_rs(
    const float* __restrict__ x, const unsigned short* __restrict__ wb,
    const float* __restrict__ bias, float* __restrict__ y,
    float* __restrict__ colsum, float* __restrict__ colsumsq) {

    __shared__ unsigned short As[BM][BK];
    __shared__ unsigned short Bs[BN][BK];

    const int t    = threadIdx.x;
    const int lane = t & 63;
    const int w    = t >> 6;
    const int wm   = w >> 1;
    const int wn   = w & 1;
    const int bm   = blockIdx.x & (Mdim / BM - 1);
    const int bn   = blockIdx.x >> 6;
    const int row0 = bm * BM;
    const int col0 = bn * BN;

    const int ar = t >> 1;
    const int ah = (t & 1) * 16;
    const float4* gA = (const float4*)(x + (size_t)(row0 + ar) * Kdim + ah);

    const unsigned short* gB0 = wb + (size_t)(col0 + (t >> 2)) * Kdim + (t & 3) * 8;
    const unsigned short* gB1 = wb + (size_t)(col0 + 64 + (t >> 2)) * Kdim + (t & 3) * 8;
    unsigned short* ldsB0 = &Bs[0][0] + t * 8;
    unsigned short* ldsB1 = &Bs[0][0] + 2048 + t * 8;

    f32x4 acc[4][4] = {};

    for (int k0 = 0; k0 < Kdim; k0 += BK) {
        __syncthreads();

        gload_lds16(gB0 + k0, ldsB0);
        gload_lds16(gB1 + k0, ldsB1);

        const int q = k0 >> 2;
        float4 f0 = gA[q + 0], f1 = gA[q + 1], f2 = gA[q + 2], f3 = gA[q + 3];
        uint4 d0, d1;
        d0.x = (unsigned)f2bf(f0.x) | ((unsigned)f2bf(f0.y) << 16);
        d0.y = (unsigned)f2bf(f0.z) | ((unsigned)f2bf(f0.w) << 16);
        d0.z = (unsigned)f2bf(f1.x) | ((unsigned)f2bf(f1.y) << 16);
        d0.w = (unsigned)f2bf(f1.z) | ((unsigned)f2bf(f1.w) << 16);
        d1.x = (unsigned)f2bf(f2.x) | ((unsigned)f2bf(f2.y) << 16);
        d1.y = (unsigned)f2bf(f2.z) | ((unsigned)f2bf(f2.w) << 16);
        d1.z = (unsigned)f2bf(f3.x) | ((unsigned)f2bf(f3.y) << 16);
        d1.w = (unsigned)f2bf(f3.z) | ((unsigned)f2bf(f3.w) << 16);
        uint4* dst = (uint4*)&As[ar][ah];
        dst[0] = d0;
        dst[1] = d1;

        __syncthreads();

        short8 af[4], bf[4];
#pragma unroll
        for (int m = 0; m < 4; ++m)
            af[m] = *(const short8*)&As[wm * 64 + m * 16 + (lane & 15)][(lane >> 4) * 8];
#pragma unroll
        for (int n = 0; n < 4; ++n)
            bf[n] = *(const short8*)&Bs[wn * 64 + n * 16 + (lane & 15)][(lane >> 4) * 8];
#pragma unroll
        for (int m = 0; m < 4; ++m)
#pragma unroll
            for (int n = 0; n < 4; ++n)
                acc[m][n] = __builtin_amdgcn_mfma_f32_16x16x32_bf16(
                    af[m], bf[n], acc[m][n], 0, 0, 0);
    }

#pragma unroll
    for (int n = 0; n < 4; ++n) {
        const int col = col0 + wn * 64 + n * 16 + (lane & 15);
        const float qb = fpq(bias[col]);
        float s = 0.0f, s2 = 0.0f;
#pragma unroll
        for (int m = 0; m < 4; ++m) {
            const int rowb = row0 + wm * 64 + m * 16 + ((lane >> 4) * 4);
#pragma unroll
            for (int j = 0; j < 4; ++j) {
                float v = fpq(acc[m][n][j]);
                v = fpq(v + qb);
                y[(size_t)(rowb + j) * Ndim + col] = v;
                s += v;
                s2 += v * v;
            }
        }
        s  += __shfl_xor(s, 16, 64);  s  += __shfl_xor(s, 32, 64);
        s2 += __shfl_xor(s2, 16, 64); s2 += __shfl_xor(s2, 32, 64);
        if (lane < 16) {
            atomicAdd(&colsum[col], s);
            atomicAdd(&colsumsq[col], s2);
        }
    }
}

// ---------------------------------------------------------------------------
// Kernel 3: per-column BN coefficients a,b
__global__ void fpbn_finalize(const float* __restrict__ colsum,
                              const float* __restrict__ colsumsq,
                              const float* __restrict__ gamma,
                              const float* __restrict__ beta,
                              float* __restrict__ a, float* __restrict__ b) {
    int i = blockIdx.x * blockDim.x + threadIdx.x;
    if (i < Ndim) {
        float mean = colsum[i] * (1.0f / Mdim);
        float var  = colsumsq[i] * (1.0f / Mdim) - mean * mean;
        float inv  = 1.0f / sqrtf(var + kEps);
        float ai   = gamma[i] * inv;
        a[i] = ai;
        b[i] = beta[i] - mean * ai;
    }
}

// ---------------------------------------------------------------------------
// Kernel 4: in-place BN apply + final quantize
__global__ void fpbn_apply(float* __restrict__ y,
                           const float* __restrict__ a,
                           const float* __restrict__ b, int n4) {
    int i = blockIdx.x * blockDim.x + threadIdx.x;
    int stride = gridDim.x * blockDim.x;
    for (; i < n4; i += stride) {
        float4 v = ((float4*)y)[i];
        int cb = (i * 4) & (Ndim - 1);
        float4 av = *(const float4*)&a[cb];
        float4 bv = *(const float4*)&b[cb];
        v.x = fpq(fmaf(av.x, v.x, bv.x));
        v.y = fpq(fmaf(av.y, v.y, bv.y));
        v.z = fpq(fmaf(av.z, v.z, bv.z));
        v.w = fpq(fmaf(av.w, v.w, bv.w));
        ((float4*)y)[i] = v;
    }
}

// ---------------------------------------------------------------------------
extern "C" void kernel_launch(void* const* d_in, const int* in_sizes, int n_in,
                              void* d_out, int out_size, void* d_ws, size_t ws_size,
                              hipStream_t stream) {
    const float* x      = (const float*)d_in[0];
    const float* weight = (const float*)d_in[1];
    const float* bias   = (const float*)d_in[2];
    const float* gamma  = (const float*)d_in[3];
    const float* beta   = (const float*)d_in[4];
    float* out = (float*)d_out;

    // ws layout: wb bf16 [8MB] | stats [64KB region] | xb bf16 [32MB]
    char* ws = (char*)d_ws;
    unsigned short* wb = (unsigned short*)ws;
    const size_t wbBytes  = (size_t)Ndim * Kdim * 2;           // 8 MB
    float* colsum   = (float*)(ws + wbBytes);
    float* colsumsq = colsum + Ndim;
    float* aArr     = colsum + 2 * Ndim;
    float* bArr     = colsum + 3 * Ndim;
    const size_t xbOff = wbBytes + 65536;
    unsigned short* xb = (unsigned short*)(ws + xbOff);
    const size_t need = xbOff + (size_t)Mdim * Kdim * 2;        // ~40.1 MB

    hipMemsetAsync(colsum, 0, 2 * Ndim * sizeof(float), stream);

    fpbn_quant_w<<<1024, 256, 0, stream>>>(weight, wb, Ndim * Kdim / 4);

    if (ws_size >= need) {
        fpbn_quant_x<<<2048, 256, 0, stream>>>(x, xb, Mdim * Kdim / 8);
        fpbn_gemm_bb<<<(Mdim / BM) * (Ndim / BN), 256, 0, stream>>>(
            xb, wb, bias, out, colsum, colsumsq);
    } else {
        fpbn_gemm_rs<<<(Mdim / BM) * (Ndim / BN), 256, 0, stream>>>(
            x, wb, bias, out, colsum, colsumsq);
    }

    fpbn_finalize<<<(Ndim + 255) / 256, 256, 0, stream>>>(
        colsum, colsumsq, gamma, beta, aArr, bArr);

    fpbn_apply<<<2048, 256, 0, stream>>>(out, aArr, bArr,
                                         Mdim * Ndim / 4);
}

// Round 5
// 226.682 us; speedup vs baseline: 1.2964x; 1.1039x over previous
//
#include <hip/hip_runtime.h>
#include <hip/hip_bf16.h>

// Problem dims (fixed by setup_inputs)
#define Mdim 8192
#define Ndim 2048
#define Kdim 2048
#define NT   32      // number of K-tiles (Kdim / 64)

constexpr float kMin = -128.0f;
constexpr float kMax = 127.99609375f;
constexpr float kScale = 256.0f;
constexpr float kInvScale = 1.0f / 256.0f;
constexpr float kEps = 1e-5f;

typedef __attribute__((ext_vector_type(8))) short short8;
typedef __attribute__((ext_vector_type(4))) float f32x4;

__device__ __forceinline__ float fpq(float x) {
    x = fminf(fmaxf(x, kMin), kMax);
    return rintf(x * kScale) * kInvScale;   // round-half-to-even, matches jnp.round
}

__device__ __forceinline__ unsigned short f2bf(float f) {
    union { __hip_bfloat16 h; unsigned short u; } cv;
    cv.h = __float2bfloat16(f);             // RNE
    return cv.u;
}

__device__ __forceinline__ void gload_lds16(const void* g, void* l) {
    __builtin_amdgcn_global_load_lds(
        (const __attribute__((address_space(1))) unsigned int*)g,
        (__attribute__((address_space(3))) unsigned int*)l,
        16, 0, 0);
}

__device__ __forceinline__ void phase_barrier() {
    __builtin_amdgcn_sched_barrier(0);
    __builtin_amdgcn_s_barrier();
    __builtin_amdgcn_sched_barrier(0);
    asm volatile("" ::: "memory");
}

__device__ __forceinline__ void wait_vmcnt4() {
    __builtin_amdgcn_sched_barrier(0);
    asm volatile("s_waitcnt vmcnt(4)" ::: "memory");
    __builtin_amdgcn_sched_barrier(0);
}

// ---------------------------------------------------------------------------
// quantize weights to fp grid, store bf16 (exact: |w|*256 < 2^8 fits bf16)
__global__ void fpbn_quant_w(const float* __restrict__ w,
                             unsigned short* __restrict__ wb, int n4) {
    int i = blockIdx.x * blockDim.x + threadIdx.x;
    int stride = gridDim.x * blockDim.x;
    for (; i < n4; i += stride) {
        float4 v = ((const float4*)w)[i];
        ushort4 o;
        o.x = f2bf(fpq(v.x));
        o.y = f2bf(fpq(v.y));
        o.z = f2bf(fpq(v.z));
        o.w = f2bf(fpq(v.w));
        ((ushort4*)wb)[i] = o;
    }
}

// x f32 -> bf16 (RNE)
__global__ void fpbn_quant_x(const float* __restrict__ x,
                             unsigned short* __restrict__ xb, int n8) {
    int i = blockIdx.x * blockDim.x + threadIdx.x;
    int stride = gridDim.x * blockDim.x;
    for (; i < n8; i += stride) {
        float4 a = ((const float4*)x)[2 * i];
        float4 b = ((const float4*)x)[2 * i + 1];
        uint4 o;
        o.x = (unsigned)f2bf(a.x) | ((unsigned)f2bf(a.y) << 16);
        o.y = (unsigned)f2bf(a.z) | ((unsigned)f2bf(a.w) << 16);
        o.z = (unsigned)f2bf(b.x) | ((unsigned)f2bf(b.y) << 16);
        o.w = (unsigned)f2bf(b.z) | ((unsigned)f2bf(b.w) << 16);
        ((uint4*)xb)[i] = o;
    }
}

// ---------------------------------------------------------------------------
// 256x256x(BK=64) 8-phase bf16 MFMA GEMM. 8 waves (2Mx4N), 512 threads.
// LDS 128 KiB: [buf2][op A/B][half2][128x64 bf16], XOR-swizzled (row&7)<<4.
// Raw barriers + counted vmcnt(4); setprio around MFMA clusters.
// Epilogue: y = fpq(fpq(acc)+qb), stats atomics; y as i16*256 (OUT16) or f32.
template <bool OUT16>
__global__ __launch_bounds__(512, 2) void fpbn_gemm8(
    const unsigned short* __restrict__ xb, const unsigned short* __restrict__ wb,
    const float* __restrict__ bias, short* __restrict__ y16,
    float* __restrict__ yf, float* __restrict__ colsum,
    float* __restrict__ colsumsq) {

    __shared__ unsigned short lds[65536];   // 128 KiB, 8 slots of 8192 elems

    const int t    = threadIdx.x;
    const int lane = t & 63;
    const int w    = t >> 6;        // 0..7
    const int wm   = w >> 2;        // 0..1  (M half of 256)
    const int wn   = w & 3;         // 0..3  (N quarter)

    const int bn   = blockIdx.x & 7;    // 8 col panels -> one per XCD
    const int bm   = blockIdx.x >> 3;   // 32 row panels
    const int row0 = bm * 256;
    const int col0 = bn * 256;

    // ---- staging source addresses (linear LDS dest, inverse-swizzled src) ----
    const int roff = t >> 3;                        // row within half: 0..63
    const int colE = ((t & 7) ^ (roff & 7)) * 8;    // swizzle-compensated col (elems)
    const unsigned short* srcA[2] = {
        xb + (size_t)(row0 +   0 + roff) * Kdim + colE,
        xb + (size_t)(row0 + 128 + roff) * Kdim + colE };
    const unsigned short* srcB[2] = {
        wb + (size_t)(col0 +   0 + roff) * Kdim + colE,
        wb + (size_t)(col0 + 128 + roff) * Kdim + colE };
    const int t8 = t * 8;

    // ---- swizzled read-side per-lane constants ----
    const int x3    = lane & 7;
    const int xk    = x3 >> 2;                 // flips kk-select (bit6 of XOR)
    const int xh    = x3 & 3;                  // flips hi-select (bits 4-5)
    const int hi    = lane >> 4;
    const int rb2   = (lane & 15) * 64 + ((hi ^ xh) * 8);
    const int k0off = xk * 32;                 // elem offset of logical kk=0
    const int k1off = 32 - k0off;              // logical kk=1
    const int bnoff = (wn & 1) * 4096;

#define STAGE(BUF_, S_, OP_, HALF_) do {                                      \
        int ss_ = (S_) < NT ? (S_) : (S_) - 2;  /* tail clamp, keeps parity */\
        const unsigned short* sp_ = (OP_ ? srcB : srcA)[HALF_] + ss_ * 64;    \
        unsigned short* dp_ =                                                 \
            &lds[(((BUF_) * 4 + (OP_) * 2 + (HALF_)) << 13) + t8];            \
        gload_lds16(sp_, dp_);                                                \
        gload_lds16(sp_ + (size_t)64 * Kdim, dp_ + 4096);                     \
    } while (0)

#define READA(BUF_, M_, KOFF_) \
    (*(const short8*)&lds[(((BUF_) * 4 + wm) << 13) + rb2 + (M_) * 1024 + (KOFF_)])
#define READB(BUF_, N_, KOFF_) \
    (*(const short8*)&lds[(((BUF_) * 4 + 2 + (wn >> 1)) << 13) + bnoff + rb2 + (N_) * 1024 + (KOFF_)])
#define MFMA_(A_, B_, C_) \
    C_ = __builtin_amdgcn_mfma_f32_16x16x32_bf16(A_, B_, C_, 0, 0, 0)

    f32x4 acc[8][4] = {};

    // prologue: tile0 all halves + tile1 A0,A1 (12 loads); 4 may stay in flight
    STAGE(0, 0, 0, 0); STAGE(0, 0, 0, 1); STAGE(0, 0, 1, 0); STAGE(0, 0, 1, 1);
    STAGE(1, 1, 0, 0); STAGE(1, 1, 0, 1);
    wait_vmcnt4();
    phase_barrier();

// One K-tile = 4 phases. Reads: P1 A(m0-3)+B(n0-1), P2 A(m4-7)+B(n2-3),
// P4 re-reads B(n0-1). All LDS of the tile consumed by P2 -> stages safe.
#define KTILE(BUF_, ST1_, ST2_, ST3_, ST4_) do {                              \
        _Pragma("unroll") for (int m = 0; m < 4; ++m) {                       \
            Af[m][0] = READA(BUF_, m, k0off);                                 \
            Af[m][1] = READA(BUF_, m, k1off); }                               \
        _Pragma("unroll") for (int n = 0; n < 2; ++n) {                       \
            Bf0[n][0] = READB(BUF_, n, k0off);                                \
            Bf0[n][1] = READB(BUF_, n, k1off); }                              \
        ST1_;                                                                 \
        phase_barrier();                                                      \
        __builtin_amdgcn_s_setprio(1);                                        \
        _Pragma("unroll") for (int m = 0; m < 4; ++m)                         \
        _Pragma("unroll") for (int n = 0; n < 2; ++n) {                       \
            MFMA_(Af[m][0], Bf0[n][0], acc[m][n]);                            \
            MFMA_(Af[m][1], Bf0[n][1], acc[m][n]); }                          \
        __builtin_amdgcn_s_setprio(0);                                        \
        phase_barrier();                                                      \
        /* P2 */                                                              \
        _Pragma("unroll") for (int m = 0; m < 4; ++m) {                       \
            Af2[m][0] = READA(BUF_, m + 4, k0off);                            \
            Af2[m][1] = READA(BUF_, m + 4, k1off); }                          \
        _Pragma("unroll") for (int n = 0; n < 2; ++n) {                       \
            Bf1[n][0] = READB(BUF_, n + 2, k0off);                            \
            Bf1[n][1] = READB(BUF_, n + 2, k1off); }                          \
        ST2_;                                                                 \
        phase_barrier();                                                      \
        __builtin_amdgcn_s_setprio(1);                                        \
        _Pragma("unroll") for (int m = 0; m < 4; ++m)                         \
        _Pragma("unroll") for (int n = 0; n < 2; ++n) {                       \
            MFMA_(Af[m][0], Bf1[n][0], acc[m][n + 2]);                        \
            MFMA_(Af[m][1], Bf1[n][1], acc[m][n + 2]); }                      \
        __builtin_amdgcn_s_setprio(0);                                        \
        phase_barrier();                                                      \
        /* P3 */                                                              \
        ST3_;                                                                 \
        phase_barrier();                                                      \
        __builtin_amdgcn_s_setprio(1);                                        \
        _Pragma("unroll") for (int m = 0; m < 4; ++m)                         \
        _Pragma("unroll") for (int n = 0; n < 2; ++n) {                       \
            MFMA_(Af2[m][0], Bf1[n][0], acc[m + 4][n + 2]);                   \
            MFMA_(Af2[m][1], Bf1[n][1], acc[m + 4][n + 2]); }                 \
        __builtin_amdgcn_s_setprio(0);                                        \
        phase_barrier();                                                      \
        /* P4 */                                                              \
        _Pragma("unroll") for (int n = 0; n < 2; ++n) {                       \
            Bf0[n][0] = READB(BUF_, n, k0off);                                \
            Bf0[n][1] = READB(BUF_, n, k1off); }                              \
        ST4_;                                                                 \
        phase_barrier();                                                      \
        __builtin_amdgcn_s_setprio(1);                                        \
        _Pragma("unroll") for (int m = 0; m < 4; ++m)                         \
        _Pragma("unroll") for (int n = 0; n < 2; ++n) {                       \
            MFMA_(Af2[m][0], Bf0[n][0], acc[m + 4][n]);                       \
            MFMA_(Af2[m][1], Bf0[n][1], acc[m + 4][n]); }                     \
        __builtin_amdgcn_s_setprio(0);                                        \
        wait_vmcnt4();                                                        \
        phase_barrier();                                                      \
    } while (0)

#pragma unroll 1
    for (int it = 0; it < NT / 2; ++it) {
        const int s0 = 2 * it;
        short8 Af[4][2], Af2[4][2], Bf0[2][2], Bf1[2][2];
        KTILE(0, STAGE(1, s0 + 1, 1, 0), STAGE(1, s0 + 1, 1, 1),
                 STAGE(0, s0 + 2, 0, 0), STAGE(0, s0 + 2, 0, 1));
        KTILE(1, STAGE(0, s0 + 2, 1, 0), STAGE(0, s0 + 2, 1, 1),
                 STAGE(1, s0 + 3, 0, 0), STAGE(1, s0 + 3, 0, 1));
    }

    // Epilogue. C/D layout: col = lane&15, row = (lane>>4)*4 + j
#pragma unroll
    for (int n = 0; n < 4; ++n) {
        const int col = col0 + wn * 64 + n * 16 + (lane & 15);
        const float qb = fpq(bias[col]);
        float s = 0.0f, s2 = 0.0f;
#pragma unroll
        for (int m = 0; m < 8; ++m) {
            const int rowb = row0 + wm * 128 + m * 16 + ((lane >> 4) * 4);
#pragma unroll
            for (int j = 0; j < 4; ++j) {
                float v = fpq(acc[m][n][j]);
                v = fpq(v + qb);
                if constexpr (OUT16)
                    y16[(size_t)(rowb + j) * Ndim + col] = (short)(v * 256.0f);
                else
                    yf[(size_t)(rowb + j) * Ndim + col] = v;
                s += v;
                s2 += v * v;
            }
        }
        s  += __shfl_xor(s, 16, 64);  s  += __shfl_xor(s, 32, 64);
        s2 += __shfl_xor(s2, 16, 64); s2 += __shfl_xor(s2, 32, 64);
        if (lane < 16) {
            atomicAdd(&colsum[col], s);
            atomicAdd(&colsumsq[col], s2);
        }
    }
#undef STAGE
#undef READA
#undef READB
#undef MFMA_
#undef KTILE
}

// ---------------------------------------------------------------------------
__global__ void fpbn_finalize(const float* __restrict__ colsum,
                              const float* __restrict__ colsumsq,
                              const float* __restrict__ gamma,
                              const float* __restrict__ beta,
                              float* __restrict__ a, float* __restrict__ b) {
    int i = blockIdx.x * blockDim.x + threadIdx.x;
    if (i < Ndim) {
        float mean = colsum[i] * (1.0f / Mdim);
        float var  = colsumsq[i] * (1.0f / Mdim) - mean * mean;
        float inv  = 1.0f / sqrtf(var + kEps);
        float ai   = gamma[i] * inv;
        a[i] = ai;
        b[i] = beta[i] - mean * ai;
    }
}

// BN apply + final quantize, i16 y -> f32 out
__global__ void fpbn_apply16(const short* __restrict__ y16,
                             float* __restrict__ out,
                             const float* __restrict__ a,
                             const float* __restrict__ b, int n8) {
    int i = blockIdx.x * blockDim.x + threadIdx.x;
    int stride = gridDim.x * blockDim.x;
    for (; i < n8; i += stride) {
        int4 raw = ((const int4*)y16)[i];      // 8 shorts
        const short* sp = (const short*)&raw;
        int cb = (i * 8) & (Ndim - 1);
        float4 a0 = *(const float4*)&a[cb], a1 = *(const float4*)&a[cb + 4];
        float4 b0 = *(const float4*)&b[cb], b1 = *(const float4*)&b[cb + 4];
        float4 o0, o1;
        o0.x = fpq(fmaf(a0.x, (float)sp[0] * kInvScale, b0.x));
        o0.y = fpq(fmaf(a0.y, (float)sp[1] * kInvScale, b0.y));
        o0.z = fpq(fmaf(a0.z, (float)sp[2] * kInvScale, b0.z));
        o0.w = fpq(fmaf(a0.w, (float)sp[3] * kInvScale, b0.w));
        o1.x = fpq(fmaf(a1.x, (float)sp[4] * kInvScale, b1.x));
        o1.y = fpq(fmaf(a1.y, (float)sp[5] * kInvScale, b1.y));
        o1.z = fpq(fmaf(a1.z, (float)sp[6] * kInvScale, b1.z));
        o1.w = fpq(fmaf(a1.w, (float)sp[7] * kInvScale, b1.w));
        ((float4*)out)[2 * i]     = o0;
        ((float4*)out)[2 * i + 1] = o1;
    }
}

// BN apply + final quantize, f32 y in-place
__global__ void fpbn_apply(float* __restrict__ y,
                           const float* __restrict__ a,
                           const float* __restrict__ b, int n4) {
    int i = blockIdx.x * blockDim.x + threadIdx.x;
    int stride = gridDim.x * blockDim.x;
    for (; i < n4; i += stride) {
        float4 v = ((float4*)y)[i];
        int cb = (i * 4) & (Ndim - 1);
        float4 av = *(const float4*)&a[cb];
        float4 bv = *(const float4*)&b[cb];
        v.x = fpq(fmaf(av.x, v.x, bv.x));
        v.y = fpq(fmaf(av.y, v.y, bv.y));
        v.z = fpq(fmaf(av.z, v.z, bv.z));
        v.w = fpq(fmaf(av.w, v.w, bv.w));
        ((float4*)y)[i] = v;
    }
}

// ---------------------------------------------------------------------------
extern "C" void kernel_launch(void* const* d_in, const int* in_sizes, int n_in,
                              void* d_out, int out_size, void* d_ws, size_t ws_size,
                              hipStream_t stream) {
    const float* x      = (const float*)d_in[0];
    const float* weight = (const float*)d_in[1];
    const float* bias   = (const float*)d_in[2];
    const float* gamma  = (const float*)d_in[3];
    const float* beta   = (const float*)d_in[4];
    float* out = (float*)d_out;

    // ws: wb bf16 [8MB] | stats [64KB] | xb bf16 [32MB] | y16 [32MB optional]
    char* ws = (char*)d_ws;
    unsigned short* wb = (unsigned short*)ws;
    const size_t wbBytes = (size_t)Ndim * Kdim * 2;
    float* colsum   = (float*)(ws + wbBytes);
    float* colsumsq = colsum + Ndim;
    float* aArr     = colsum + 2 * Ndim;
    float* bArr     = colsum + 3 * Ndim;
    const size_t xbOff = wbBytes + 65536;
    unsigned short* xb = (unsigned short*)(ws + xbOff);
    const size_t xbBytes  = (size_t)Mdim * Kdim * 2;
    const size_t y16Off   = xbOff + xbBytes;
    short* y16 = (short*)(ws + y16Off);
    const size_t need16 = y16Off + (size_t)Mdim * Ndim * 2;   // ~72.1 MB

    hipMemsetAsync(colsum, 0, 2 * Ndim * sizeof(float), stream);

    fpbn_quant_w<<<1024, 256, 0, stream>>>(weight, wb, Ndim * Kdim / 4);
    fpbn_quant_x<<<2048, 256, 0, stream>>>(x, xb, Mdim * Kdim / 8);

    if (ws_size >= need16) {
        fpbn_gemm8<true><<<(Mdim / 256) * (Ndim / 256), 512, 0, stream>>>(
            xb, wb, bias, y16, nullptr, colsum, colsumsq);
        fpbn_finalize<<<(Ndim + 255) / 256, 256, 0, stream>>>(
            colsum, colsumsq, gamma, beta, aArr, bArr);
        fpbn_apply16<<<2048, 256, 0, stream>>>(y16, out, aArr, bArr,
                                               Mdim * Ndim / 8);
    } else {
        fpbn_gemm8<false><<<(Mdim / 256) * (Ndim / 256), 512, 0, stream>>>(
            xb, wb, bias, nullptr, out, colsum, colsumsq);
        fpbn_finalize<<<(Ndim + 255) / 256, 256, 0, stream>>>(
            colsum, colsumsq, gamma, beta, aArr, bArr);
        fpbn_apply<<<2048, 256, 0, stream>>>(out, aArr, bArr, Mdim * Ndim / 4);
    }
}